// Round 8
// baseline (775.627 us; speedup 1.0000x reference)
//
#include <hip/hip_runtime.h>

// FINER MLP fused forward: 3 -> [256 x5 sin(30*(1+|z|)*z)] -> 1, 1M points.
// Layer 0: fp32 VALU. Layers 1-4: fp16 MFMA 32x32x16, activations entirely in
// registers (points-in-lanes, permlane32_swap repack). Layer 5: fp16 MFMA
// row-dot. W stream: 64 contiguous 8KB slices staged via global_load_lds into
// a 6-slot LDS ring. CHANGES vs R4 (both schedule-local, math identical):
//  (1) 2-slice barrier windows: 32 windows x {vmcnt(2), s_barrier, stage 2,
//      16 ds_read + 16 MFMA} instead of 64 x {vmcnt(4), 1 slice, 8 MFMA}.
//  (2) s_setprio(1) around each 16-MFMA cluster.

typedef _Float16 f16;
typedef _Float16 f16x8 __attribute__((ext_vector_type(8)));
typedef float f32x16 __attribute__((ext_vector_type(16)));
typedef unsigned int u32;
typedef u32 u32x4 __attribute__((ext_vector_type(4)));

#define C_REV 4.77464829275686f  // 30 / (2*pi)
#define RING  6                  // slices in ring
#define DEPTH 4                  // slices staged ahead (2 windows)

// workspace layout (bytes):
//  [0, 524288): hidden W fp16, 64 slices of 8KB: slice s = (layer l)*16 + kc,
//     within slice 16B frag at slot' = slot ^ ((slot>>3)&7), slot = 2*o + h,
//     frag = W_{l+1}[o][16kc+8h .. +8)
//  [524288, +4096): W0B float4[256] = {W0[o][0..2], b0[o]}
//  [528384, +512): W5 fp16[256]
#define WS_W0B_BYTE    524288
#define WS_W5_HALF     (528384 / 2)

__device__ __forceinline__ float finer_act(float z) {
  float zz = __builtin_fmaf(z, __builtin_fabsf(z), z);   // z * (1 + |z|)
  float rv = zz * C_REV;                                 // revolutions
  float fr = rv - __builtin_rintf(rv);                   // [-0.5, 0.5]
  return __builtin_amdgcn_sinf(fr);                      // sin(2*pi*fr)
}

__device__ __forceinline__ u32 pk2(float a, float b) {   // RTN f16 pack
  union { f16 h; unsigned short u; } ua, ub;
  ua.h = (f16)a; ub.h = (f16)b;
  return ((u32)ub.u << 16) | (u32)ua.u;
}

__device__ __forceinline__ void swap_halves(u32 &x, u32 &y) {
  // x[32..63] <-> y[0..31]  =>  x' = [x_lo | y_lo], y' = [x_hi | y_hi]
  asm volatile("v_permlane32_swap_b32 %0, %1" : "+v"(x), "+v"(y));
}

typedef const __attribute__((address_space(1))) u32 gu32;
typedef __attribute__((address_space(3))) u32 lu32;

__device__ __forceinline__ void stage_slice(const f16* g_slice, f16* lds_buf, int tid) {
  // copy one 8KB W slice: 512 threads x 16B; LDS dest = wave-uniform base + lane*16
  const f16* g = g_slice + tid * 8;
  f16* l = lds_buf + (tid >> 6) * 512;   // 1KB per wave
  __builtin_amdgcn_global_load_lds((gu32*)g, (lu32*)l, 16, 0, 0);
}

__global__ void finer_prep(const float* __restrict__ W1, const float* __restrict__ W2,
                           const float* __restrict__ W3, const float* __restrict__ W4,
                           const float* __restrict__ W0, const float* __restrict__ b0,
                           const float* __restrict__ W5, f16* __restrict__ ws)
{
  if (blockIdx.x < 64) {
    const int tid = blockIdx.x * 256 + threadIdx.x;   // 0..16383: l(2) kc(4) o(8)
    const int l  = tid >> 12;
    const int kc = (tid >> 8) & 15;
    const int o  = tid & 255;
    const float* W = (l == 0) ? W1 : (l == 1) ? W2 : (l == 2) ? W3 : W4;
    const float* src = W + o * 256 + kc * 16;
    f16* base = ws + (l * 16 + kc) * 4096;
    #pragma unroll
    for (int h = 0; h < 2; ++h) {
      const int slot = o * 2 + h;
      const int swz  = slot ^ ((slot >> 3) & 7);   // bank-spread involution
      f16* dst = base + swz * 8;
      #pragma unroll
      for (int j = 0; j < 8; ++j) dst[j] = (f16)src[h * 8 + j];
    }
  } else {
    const int o = threadIdx.x;   // 0..255
    float4* w0b = (float4*)((char*)ws + WS_W0B_BYTE);
    float4 v;
    v.x = W0[o * 3 + 0]; v.y = W0[o * 3 + 1]; v.z = W0[o * 3 + 2]; v.w = b0[o];
    w0b[o] = v;
    ws[WS_W5_HALF + o] = (f16)W5[o];
  }
}

__global__ __launch_bounds__(512, 2)
void finer_fused(const float* __restrict__ coords,
                 const float* __restrict__ b1, const float* __restrict__ b2,
                 const float* __restrict__ b3, const float* __restrict__ b4,
                 const float* __restrict__ b5p,
                 const f16* __restrict__ ws,
                 float* __restrict__ out, int N)
{
  __shared__ __align__(16) f16 Wbuf[RING][4096];  // 6 x 8KB W slice ring
  __shared__ float4 sW0B[256];                    // {W0 row, b0}
  __shared__ __align__(16) float sb[4][256];      // b1..b4

  const int tid  = threadIdx.x;
  const int lane = tid & 63;
  const int wid  = tid >> 6;
  const int h    = lane >> 5;     // half-wave
  const int col  = lane & 31;     // point-within-wave (MFMA N/col index)
  const int m    = blockIdx.x * 256 + wid * 32 + col;   // point id
  const int mc   = (m < N) ? m : (N - 1);

  if (tid < 256) {
    const float4* w0bg = (const float4*)((const char*)ws + WS_W0B_BYTE);
    sW0B[tid] = w0bg[tid];
    sb[0][tid] = b1[tid];
    sb[1][tid] = b2[tid];
    sb[2][tid] = b3[tid];
    sb[3][tid] = b4[tid];
  }
  __syncthreads();   // tables visible (full drain fine: nothing staged yet)

  // prologue: fill the ring DEPTH slices deep; layer-0 VALU hides the latency
  #pragma unroll
  for (int s = 0; s < DEPTH; ++s)
    stage_slice(ws + s * 4096, &Wbuf[s][0], tid);

  // ---------------- layer 0 (3 -> 256), fp32 VALU ----------------
  const float c0 = coords[mc * 3 + 0];
  const float c1 = coords[mc * 3 + 1];
  const float c2 = coords[mc * 3 + 2];

  // actu[kc] = B fragment for K-window [16kc,16kc+16): lane holds
  // act[point m][k = 16kc + 8h + j], j=0..7, packed 2 f16 per u32.
  u32x4 actu[16];
  #pragma unroll
  for (int kc = 0; kc < 16; ++kc) {
    float s[8];
    #pragma unroll
    for (int j = 0; j < 8; ++j) {
      const float4 q = sW0B[kc * 16 + h * 8 + j];
      const float z = __builtin_fmaf(c0, q.x,
                        __builtin_fmaf(c1, q.y,
                          __builtin_fmaf(c2, q.z, q.w)));
      s[j] = finer_act(z);
    }
    actu[kc][0] = pk2(s[0], s[1]);
    actu[kc][1] = pk2(s[2], s[3]);
    actu[kc][2] = pk2(s[4], s[5]);
    actu[kc][3] = pk2(s[6], s[7]);
  }

  // per-lane swizzled fragment offset (f16 units); f adds 512 within a slice
  const int fragoff = ((2 * col + h) ^ ((col >> 2) & 7)) * 8;

  // ---------------- hidden layers (256 -> 256) x4, fp16 MFMA ----------------
  // Z^T = W * X^T: A = W tile (row o in lanes), B = activations (point in lanes).
  f32x16 acc[8];
  #pragma unroll
  for (int layer = 0; layer < 4; ++layer) {
    #pragma unroll
    for (int f = 0; f < 8; ++f)
      #pragma unroll
      for (int r = 0; r < 16; ++r) acc[f][r] = 0.0f;

    #pragma unroll
    for (int w = 0; w < 8; ++w) {                 // 2-slice window
      const int t  = layer * 8 + w;               // global window index, 0..31
      const int s0 = 2 * t;                       // slices consumed this window
      const int s1 = 2 * t + 1;
      // loads for s0,s1 landed (loads for s0+2,s0+3 may stay in flight)
      asm volatile("s_waitcnt vmcnt(2)" ::: "memory");
      __builtin_amdgcn_s_barrier();               // all waves see s0,s1;
      __builtin_amdgcn_sched_barrier(0);          // slots (s0+4)%6,(s1+4)%6 free
      {
        const int n0 = (s0 + 4 < 64) ? (s0 + 4) : 63;   // clamp: dead-slot dup
        const int n1 = (s1 + 4 < 64) ? (s1 + 4) : 63;
        stage_slice(ws + n0 * 4096, &Wbuf[(s0 + 4) % RING][0], tid);
        stage_slice(ws + n1 * 4096, &Wbuf[(s1 + 4) % RING][0], tid);
      }
      const f16x8 bf0 = __builtin_bit_cast(f16x8, actu[2 * w + 0]);
      const f16x8 bf1 = __builtin_bit_cast(f16x8, actu[2 * w + 1]);
      __builtin_amdgcn_s_setprio(1);
      #pragma unroll
      for (int f = 0; f < 8; ++f) {
        const f16x8 wf0 = *(const f16x8*)&Wbuf[s0 % RING][fragoff + f * 512];
        acc[f] = __builtin_amdgcn_mfma_f32_32x32x16_f16(wf0, bf0, acc[f], 0, 0, 0);
        const f16x8 wf1 = *(const f16x8*)&Wbuf[s1 % RING][fragoff + f * 512];
        acc[f] = __builtin_amdgcn_mfma_f32_32x32x16_f16(wf1, bf1, acc[f], 0, 0, 0);
      }
      __builtin_amdgcn_s_setprio(0);
    }

    // activation + repack into next-layer B fragments (registers only)
    const float* sbrow = sb[layer];
    #pragma unroll
    for (int f = 0; f < 8; ++f) {
      u32 P[4][2];
      #pragma unroll
      for (int i2 = 0; i2 < 4; ++i2) {
        const int o0 = 32 * f + 8 * i2 + 4 * h;   // feature base of this quad
        const float4 bq = *(const float4*)&sbrow[o0];
        const float s0 = finer_act(acc[f][4 * i2 + 0] + bq.x);
        const float s1 = finer_act(acc[f][4 * i2 + 1] + bq.y);
        const float s2 = finer_act(acc[f][4 * i2 + 2] + bq.z);
        const float s3 = finer_act(acc[f][4 * i2 + 3] + bq.w);
        P[i2][0] = pk2(s0, s1);
        P[i2][1] = pk2(s2, s3);
      }
      u32 t00 = P[0][0], t02 = P[1][0]; swap_halves(t00, t02);
      u32 t01 = P[0][1], t03 = P[1][1]; swap_halves(t01, t03);
      u32 t10 = P[2][0], t12 = P[3][0]; swap_halves(t10, t12);
      u32 t11 = P[2][1], t13 = P[3][1]; swap_halves(t11, t13);
      actu[2 * f + 0][0] = t00; actu[2 * f + 0][1] = t01;
      actu[2 * f + 0][2] = t02; actu[2 * f + 0][3] = t03;
      actu[2 * f + 1][0] = t10; actu[2 * f + 1][1] = t11;
      actu[2 * f + 1][2] = t12; actu[2 * f + 1][3] = t13;
    }
  }

  // ---------------- layer 5 (256 -> 1), fp16 MFMA row-dot ----------------
  f32x16 acc5;
  #pragma unroll
  for (int r = 0; r < 16; ++r) acc5[r] = 0.0f;
  const f16* w5 = ws + WS_W5_HALF;
  #pragma unroll
  for (int kc = 0; kc < 16; ++kc) {
    f16x8 wf;
    #pragma unroll
    for (int j = 0; j < 8; ++j) wf[j] = (f16)0.0f;
    if (col == 0) wf = *(const f16x8*)&w5[kc * 16 + h * 8];   // A row 0 = W5
    const f16x8 bf = __builtin_bit_cast(f16x8, actu[kc]);
    acc5 = __builtin_amdgcn_mfma_f32_32x32x16_f16(wf, bf, acc5, 0, 0, 0);
  }
  // C row 0 lives in reg 0 of half-wave 0; col = point
  if (h == 0 && m < N) out[m] = acc5[0] + b5p[0];
}

extern "C" void kernel_launch(void* const* d_in, const int* in_sizes, int n_in,
                              void* d_out, int out_size, void* d_ws, size_t ws_size,
                              hipStream_t stream) {
  const float* coords = (const float*)d_in[0];
  const float* W0 = (const float*)d_in[1];
  const float* b0 = (const float*)d_in[2];
  const float* W1 = (const float*)d_in[3];
  const float* b1 = (const float*)d_in[4];
  const float* W2 = (const float*)d_in[5];
  const float* b2 = (const float*)d_in[6];
  const float* W3 = (const float*)d_in[7];
  const float* b3 = (const float*)d_in[8];
  const float* W4 = (const float*)d_in[9];
  const float* b4 = (const float*)d_in[10];
  const float* W5 = (const float*)d_in[11];
  const float* b5 = (const float*)d_in[12];
  f16* ws = (f16*)d_ws;
  float* out = (float*)d_out;
  const int N = in_sizes[0] / 3;

  finer_prep<<<65, 256, 0, stream>>>(W1, W2, W3, W4, W0, b0, W5, ws);
  const int nblk = (N + 255) / 256;
  finer_fused<<<nblk, 512, 0, stream>>>(coords, b1, b2, b3, b4, b5, ws, out, N);
}

// Round 9
// 696.198 us; speedup vs baseline: 1.1141x; 1.1141x over previous
//
#include <hip/hip_runtime.h>

// FINER MLP fused forward: 3 -> [256 x5 sin(30*(1+|z|)*z)] -> 1, 1M points.
// Layer 0: fp32 VALU. Layers 1-4: fp16 MFMA 32x32x16, activations entirely in
// registers (points-in-lanes, permlane32_swap repack). Layer 5: fp16 MFMA
// row-dot. W stream: 64 contiguous 8KB slices staged via global_load_lds into
// a 6-slot LDS ring; 2-slice barrier windows with counted vmcnt(2) + setprio.
// CHANGES vs R8 (arithmetic only, schedule/memory identical):
//  (1) finer_act: v_fract range reduction (1 instr) instead of rndne+sub.
//  (2) hidden-layer bias folded into MFMA acc init (epilogue add removed).
//  (3) pk2 via f16x2 vector build (RTN preserved; enables v_pack_b32_f16).

typedef _Float16 f16;
typedef _Float16 f16x2 __attribute__((ext_vector_type(2)));
typedef _Float16 f16x8 __attribute__((ext_vector_type(8)));
typedef float f32x16 __attribute__((ext_vector_type(16)));
typedef unsigned int u32;
typedef u32 u32x4 __attribute__((ext_vector_type(4)));

#define C_REV 4.77464829275686f  // 30 / (2*pi)
#define RING  6                  // slices in ring
#define DEPTH 4                  // slices staged ahead (2 windows)

// workspace layout (bytes):
//  [0, 524288): hidden W fp16, 64 slices of 8KB: slice s = (layer l)*16 + kc,
//     within slice 16B frag at slot' = slot ^ ((slot>>3)&7), slot = 2*o + h,
//     frag = W_{l+1}[o][16kc+8h .. +8)
//  [524288, +4096): W0B float4[256] = {W0[o][0..2], b0[o]}
//  [528384, +512): W5 fp16[256]
#define WS_W0B_BYTE    524288
#define WS_W5_HALF     (528384 / 2)

__device__ __forceinline__ float finer_act(float z) {
  float zz = __builtin_fmaf(z, __builtin_fabsf(z), z);   // z * (1 + |z|)
  float rv = zz * C_REV;                                 // revolutions
  float fr = __builtin_amdgcn_fractf(rv);                // exact period shift
  return __builtin_amdgcn_sinf(fr);                      // sin(2*pi*fr)
}

__device__ __forceinline__ u32 pk2(float a, float b) {   // RTN f16 pack
  f16x2 v;
  v[0] = (f16)a;
  v[1] = (f16)b;
  return __builtin_bit_cast(u32, v);
}

__device__ __forceinline__ void swap_halves(u32 &x, u32 &y) {
  // x[32..63] <-> y[0..31]  =>  x' = [x_lo | y_lo], y' = [x_hi | y_hi]
  asm volatile("v_permlane32_swap_b32 %0, %1" : "+v"(x), "+v"(y));
}

typedef const __attribute__((address_space(1))) u32 gu32;
typedef __attribute__((address_space(3))) u32 lu32;

__device__ __forceinline__ void stage_slice(const f16* g_slice, f16* lds_buf, int tid) {
  // copy one 8KB W slice: 512 threads x 16B; LDS dest = wave-uniform base + lane*16
  const f16* g = g_slice + tid * 8;
  f16* l = lds_buf + (tid >> 6) * 512;   // 1KB per wave
  __builtin_amdgcn_global_load_lds((gu32*)g, (lu32*)l, 16, 0, 0);
}

__global__ void finer_prep(const float* __restrict__ W1, const float* __restrict__ W2,
                           const float* __restrict__ W3, const float* __restrict__ W4,
                           const float* __restrict__ W0, const float* __restrict__ b0,
                           const float* __restrict__ W5, f16* __restrict__ ws)
{
  if (blockIdx.x < 64) {
    const int tid = blockIdx.x * 256 + threadIdx.x;   // 0..16383: l(2) kc(4) o(8)
    const int l  = tid >> 12;
    const int kc = (tid >> 8) & 15;
    const int o  = tid & 255;
    const float* W = (l == 0) ? W1 : (l == 1) ? W2 : (l == 2) ? W3 : W4;
    const float* src = W + o * 256 + kc * 16;
    f16* base = ws + (l * 16 + kc) * 4096;
    #pragma unroll
    for (int h = 0; h < 2; ++h) {
      const int slot = o * 2 + h;
      const int swz  = slot ^ ((slot >> 3) & 7);   // bank-spread involution
      f16* dst = base + swz * 8;
      #pragma unroll
      for (int j = 0; j < 8; ++j) dst[j] = (f16)src[h * 8 + j];
    }
  } else {
    const int o = threadIdx.x;   // 0..255
    float4* w0b = (float4*)((char*)ws + WS_W0B_BYTE);
    float4 v;
    v.x = W0[o * 3 + 0]; v.y = W0[o * 3 + 1]; v.z = W0[o * 3 + 2]; v.w = b0[o];
    w0b[o] = v;
    ws[WS_W5_HALF + o] = (f16)W5[o];
  }
}

__global__ __launch_bounds__(512, 2)
void finer_fused(const float* __restrict__ coords,
                 const float* __restrict__ b1, const float* __restrict__ b2,
                 const float* __restrict__ b3, const float* __restrict__ b4,
                 const float* __restrict__ b5p,
                 const f16* __restrict__ ws,
                 float* __restrict__ out, int N)
{
  __shared__ __align__(16) f16 Wbuf[RING][4096];  // 6 x 8KB W slice ring
  __shared__ float4 sW0B[256];                    // {W0 row, b0}
  __shared__ __align__(16) float sb[4][256];      // b1..b4

  const int tid  = threadIdx.x;
  const int lane = tid & 63;
  const int wid  = tid >> 6;
  const int h    = lane >> 5;     // half-wave
  const int col  = lane & 31;     // point-within-wave (MFMA N/col index)
  const int m    = blockIdx.x * 256 + wid * 32 + col;   // point id
  const int mc   = (m < N) ? m : (N - 1);

  if (tid < 256) {
    const float4* w0bg = (const float4*)((const char*)ws + WS_W0B_BYTE);
    sW0B[tid] = w0bg[tid];
    sb[0][tid] = b1[tid];
    sb[1][tid] = b2[tid];
    sb[2][tid] = b3[tid];
    sb[3][tid] = b4[tid];
  }
  __syncthreads();   // tables visible (full drain fine: nothing staged yet)

  // prologue: fill the ring DEPTH slices deep; layer-0 VALU hides the latency
  #pragma unroll
  for (int s = 0; s < DEPTH; ++s)
    stage_slice(ws + s * 4096, &Wbuf[s][0], tid);

  // ---------------- layer 0 (3 -> 256), fp32 VALU ----------------
  const float c0 = coords[mc * 3 + 0];
  const float c1 = coords[mc * 3 + 1];
  const float c2 = coords[mc * 3 + 2];

  // actu[kc] = B fragment for K-window [16kc,16kc+16): lane holds
  // act[point m][k = 16kc + 8h + j], j=0..7, packed 2 f16 per u32.
  u32x4 actu[16];
  #pragma unroll
  for (int kc = 0; kc < 16; ++kc) {
    float s[8];
    #pragma unroll
    for (int j = 0; j < 8; ++j) {
      const float4 q = sW0B[kc * 16 + h * 8 + j];
      const float z = __builtin_fmaf(c0, q.x,
                        __builtin_fmaf(c1, q.y,
                          __builtin_fmaf(c2, q.z, q.w)));
      s[j] = finer_act(z);
    }
    actu[kc][0] = pk2(s[0], s[1]);
    actu[kc][1] = pk2(s[2], s[3]);
    actu[kc][2] = pk2(s[4], s[5]);
    actu[kc][3] = pk2(s[6], s[7]);
  }

  // per-lane swizzled fragment offset (f16 units); f adds 512 within a slice
  const int fragoff = ((2 * col + h) ^ ((col >> 2) & 7)) * 8;

  // ---------------- hidden layers (256 -> 256) x4, fp16 MFMA ----------------
  // Z^T = W * X^T: A = W tile (row o in lanes), B = activations (point in lanes).
  f32x16 acc[8];
  #pragma unroll
  for (int layer = 0; layer < 4; ++layer) {
    // acc init = bias (replaces zero-init + epilogue add); sb is read-only
    const float* sbrow = sb[layer];
    #pragma unroll
    for (int f = 0; f < 8; ++f)
      #pragma unroll
      for (int i2 = 0; i2 < 4; ++i2) {
        const float4 bq = *(const float4*)&sbrow[32 * f + 8 * i2 + 4 * h];
        acc[f][4 * i2 + 0] = bq.x;
        acc[f][4 * i2 + 1] = bq.y;
        acc[f][4 * i2 + 2] = bq.z;
        acc[f][4 * i2 + 3] = bq.w;
      }

    #pragma unroll
    for (int w = 0; w < 8; ++w) {                 // 2-slice window
      const int t  = layer * 8 + w;               // global window index, 0..31
      const int s0 = 2 * t;                       // slices consumed this window
      const int s1 = 2 * t + 1;
      // loads for s0,s1 landed (loads for s0+2,s0+3 may stay in flight)
      asm volatile("s_waitcnt vmcnt(2)" ::: "memory");
      __builtin_amdgcn_s_barrier();               // all waves see s0,s1;
      __builtin_amdgcn_sched_barrier(0);          // slots (s0+4)%6,(s1+4)%6 free
      {
        const int n0 = (s0 + 4 < 64) ? (s0 + 4) : 63;   // clamp: dead-slot dup
        const int n1 = (s1 + 4 < 64) ? (s1 + 4) : 63;
        stage_slice(ws + n0 * 4096, &Wbuf[(s0 + 4) % RING][0], tid);
        stage_slice(ws + n1 * 4096, &Wbuf[(s1 + 4) % RING][0], tid);
      }
      const f16x8 bf0 = __builtin_bit_cast(f16x8, actu[2 * w + 0]);
      const f16x8 bf1 = __builtin_bit_cast(f16x8, actu[2 * w + 1]);
      __builtin_amdgcn_s_setprio(1);
      #pragma unroll
      for (int f = 0; f < 8; ++f) {
        const f16x8 wf0 = *(const f16x8*)&Wbuf[s0 % RING][fragoff + f * 512];
        acc[f] = __builtin_amdgcn_mfma_f32_32x32x16_f16(wf0, bf0, acc[f], 0, 0, 0);
        const f16x8 wf1 = *(const f16x8*)&Wbuf[s1 % RING][fragoff + f * 512];
        acc[f] = __builtin_amdgcn_mfma_f32_32x32x16_f16(wf1, bf1, acc[f], 0, 0, 0);
      }
      __builtin_amdgcn_s_setprio(0);
    }

    // activation + repack into next-layer B fragments (registers only)
    #pragma unroll
    for (int f = 0; f < 8; ++f) {
      u32 P[4][2];
      #pragma unroll
      for (int i2 = 0; i2 < 4; ++i2) {
        const float s0 = finer_act(acc[f][4 * i2 + 0]);
        const float s1 = finer_act(acc[f][4 * i2 + 1]);
        const float s2 = finer_act(acc[f][4 * i2 + 2]);
        const float s3 = finer_act(acc[f][4 * i2 + 3]);
        P[i2][0] = pk2(s0, s1);
        P[i2][1] = pk2(s2, s3);
      }
      u32 t00 = P[0][0], t02 = P[1][0]; swap_halves(t00, t02);
      u32 t01 = P[0][1], t03 = P[1][1]; swap_halves(t01, t03);
      u32 t10 = P[2][0], t12 = P[3][0]; swap_halves(t10, t12);
      u32 t11 = P[2][1], t13 = P[3][1]; swap_halves(t11, t13);
      actu[2 * f + 0][0] = t00; actu[2 * f + 0][1] = t01;
      actu[2 * f + 0][2] = t02; actu[2 * f + 0][3] = t03;
      actu[2 * f + 1][0] = t10; actu[2 * f + 1][1] = t11;
      actu[2 * f + 1][2] = t12; actu[2 * f + 1][3] = t13;
    }
  }

  // ---------------- layer 5 (256 -> 1), fp16 MFMA row-dot ----------------
  f32x16 acc5;
  #pragma unroll
  for (int r = 0; r < 16; ++r) acc5[r] = 0.0f;
  const f16* w5 = ws + WS_W5_HALF;
  #pragma unroll
  for (int kc = 0; kc < 16; ++kc) {
    f16x8 wf;
    #pragma unroll
    for (int j = 0; j < 8; ++j) wf[j] = (f16)0.0f;
    if (col == 0) wf = *(const f16x8*)&w5[kc * 16 + h * 8];   // A row 0 = W5
    const f16x8 bf = __builtin_bit_cast(f16x8, actu[kc]);
    acc5 = __builtin_amdgcn_mfma_f32_32x32x16_f16(wf, bf, acc5, 0, 0, 0);
  }
  // C row 0 lives in reg 0 of half-wave 0; col = point
  if (h == 0 && m < N) out[m] = acc5[0] + b5p[0];
}

extern "C" void kernel_launch(void* const* d_in, const int* in_sizes, int n_in,
                              void* d_out, int out_size, void* d_ws, size_t ws_size,
                              hipStream_t stream) {
  const float* coords = (const float*)d_in[0];
  const float* W0 = (const float*)d_in[1];
  const float* b0 = (const float*)d_in[2];
  const float* W1 = (const float*)d_in[3];
  const float* b1 = (const float*)d_in[4];
  const float* W2 = (const float*)d_in[5];
  const float* b2 = (const float*)d_in[6];
  const float* W3 = (const float*)d_in[7];
  const float* b3 = (const float*)d_in[8];
  const float* W4 = (const float*)d_in[9];
  const float* b4 = (const float*)d_in[10];
  const float* W5 = (const float*)d_in[11];
  const float* b5 = (const float*)d_in[12];
  f16* ws = (f16*)d_ws;
  float* out = (float*)d_out;
  const int N = in_sizes[0] / 3;

  finer_prep<<<65, 256, 0, stream>>>(W1, W2, W3, W4, W0, b0, W5, ws);
  const int nblk = (N + 255) / 256;
  finer_fused<<<nblk, 512, 0, stream>>>(coords, b1, b2, b3, b4, b5, ws, out, N);
}